// Round 9
// baseline (199.629 us; speedup 1.0000x reference)
//
#include <hip/hip_runtime.h>

// Problem constants
#define V_SZ 32000
#define E_SZ 128
#define H_SZ 32
#define L_SZ 64
#define B_SZ 32
#define M_TOT 2048   // L*B rows
#define K2 64        // 2H
#define NVT 125      // V/256 col-slices
#define NQ4 (M_TOT * (V_SZ / 4))   // f32x4 units in output

typedef __bf16 bf16x8 __attribute__((ext_vector_type(8)));
typedef float f32x4 __attribute__((ext_vector_type(4)));
typedef unsigned short u16x4 __attribute__((ext_vector_type(4)));

__device__ __forceinline__ unsigned short f2bf(float f) {
    unsigned int u = __float_as_uint(f);
    u += 0x7FFFu + ((u >> 16) & 1u);   // round-to-nearest-even
    return (unsigned short)(u >> 16);
}
__device__ __forceinline__ float bf2f(unsigned short u) {
    return __uint_as_float((unsigned int)u << 16);
}

// ---------------------------------------------------------------------------
// R6/R8-proven helpers: B fragments resident before MFMA (MLP), tile GEMM.
// C layout: row = wm*32 + m*16 + lg*4 + r, col = wn*128 + n*16 + lr.
// ---------------------------------------------------------------------------
__device__ __forceinline__ void load_bfrag(
    const __bf16* __restrict__ h2oT, int xcol, int wn, int lg, int lr,
    bf16x8 bfr[8][2]) {
    const int colbase = xcol * 256;
#pragma unroll
    for (int n = 0; n < 8; ++n) {
        int col = colbase + wn * 128 + n * 16 + lr;
        const __bf16* bp = h2oT + (size_t)col * K2 + lg * 8;
        bfr[n][0] = *(const bf16x8*)(bp);
        bfr[n][1] = *(const bf16x8*)(bp + 32);
    }
}

__device__ __forceinline__ void tile_gemm(
    const __bf16* __restrict__ hcat, int rowbase, int wm, int lg, int lr,
    const bf16x8 bfr[8][2], f32x4 acc[2][8]) {
    bf16x8 af[2][2];
#pragma unroll
    for (int m = 0; m < 2; ++m) {
        int row = rowbase + wm * 32 + m * 16 + lr;
#pragma unroll
        for (int kh = 0; kh < 2; ++kh)
            af[m][kh] = *(const bf16x8*)(hcat + row * K2 + kh * 32 + lg * 8);
    }
#pragma unroll
    for (int m = 0; m < 2; ++m)
#pragma unroll
        for (int n = 0; n < 8; ++n) acc[m][n] = (f32x4){0.f, 0.f, 0.f, 0.f};
#pragma unroll
    for (int n = 0; n < 8; ++n)
#pragma unroll
        for (int m = 0; m < 2; ++m) {
            acc[m][n] = __builtin_amdgcn_mfma_f32_16x16x32_bf16(af[m][0], bfr[n][0], acc[m][n], 0, 0, 0);
            acc[m][n] = __builtin_amdgcn_mfma_f32_16x16x32_bf16(af[m][1], bfr[n][1], acc[m][n], 0, 0, 0);
        }
}

// ---------------------------------------------------------------------------
// Kernel 1: blocks 0..124  -> transpose+convert h2o -> h2oT (256 rows each)
//           blocks 125..156 -> emb-GEMM into LDS + RNN recurrence
// (unchanged, proven since R6)
// ---------------------------------------------------------------------------
__global__ __launch_bounds__(256) void k_prep_rnn(
    const int* __restrict__ inp, const float* __restrict__ we,
    const float* __restrict__ i2h1, const float* __restrict__ i2h2,
    const float* __restrict__ h2o, const float* __restrict__ bias,
    const float* __restrict__ hinit,
    unsigned short* __restrict__ hcat_u, unsigned short* __restrict__ h2oT_u) {
    const int tid = threadIdx.x;
    const int p = blockIdx.x;
    if (p < 125) {
        const int v = p * 256 + tid;               // [0,32000) exact
        unsigned int* dst = (unsigned int*)(h2oT_u + (size_t)v * K2);
#pragma unroll
        for (int k = 0; k < K2; k += 2) {
            float a = h2o[(size_t)k * V_SZ + v];
            float b = h2o[(size_t)(k + 1) * V_SZ + v];
            dst[k >> 1] = (unsigned int)f2bf(a) | ((unsigned int)f2bf(b) << 16);
        }
        return;
    }
    // ---- emb + RNN block (one direction, 2 batch rows) ----
    const int w2 = p - 125;                        // 0..31
    const int dir = w2 >> 4;
    const int bpair = w2 & 15;
    const float* W = dir ? i2h2 : i2h1;
    __shared__ float Xl[L_SZ * 2 * H_SZ];          // 16 KB: X[t][bb][j]
    {
        const int j = tid & 31, bb = (tid >> 5) & 1, to = tid >> 6;
        const int b = bpair * 2 + bb;
        const float bj = bias[j];
        for (int tt = 0; tt < 16; ++tt) {
            const int t = to * 16 + tt;
            const int idx = inp[t * B_SZ + b];
            const float* er = we + (size_t)idx * E_SZ;
            float acc = bj;
#pragma unroll
            for (int k0 = 0; k0 < E_SZ; k0 += 4) {
                f32x4 e4 = *(const f32x4*)(er + k0);
                acc += e4.x * W[(k0 + 0) * H_SZ + j];
                acc += e4.y * W[(k0 + 1) * H_SZ + j];
                acc += e4.z * W[(k0 + 2) * H_SZ + j];
                acc += e4.w * W[(k0 + 3) * H_SZ + j];
            }
            Xl[(t * 2 + bb) * H_SZ + j] = acc;
        }
    }
    __syncthreads();
    if (tid < 64) {
        const int lane = tid;
        const int bb = lane >> 5;
        const int b = bpair * 2 + bb;
        const int j = lane & 31;
        const int srcbase = lane & 32;
        float wh[H_SZ];
#pragma unroll
        for (int k = 0; k < H_SZ; ++k) wh[k] = W[(E_SZ + k) * H_SZ + j];
        float h = hinit[j];
        for (int step = 0; step < L_SZ; ++step) {
            const int tt = dir ? (L_SZ - 1 - step) : step;
            hcat_u[(tt * B_SZ + b) * K2 + dir * H_SZ + j] = f2bf(h);
            float a0 = Xl[(tt * 2 + bb) * H_SZ + j];
            float a1 = 0.f, a2 = 0.f, a3 = 0.f;
#pragma unroll
            for (int k = 0; k < H_SZ; k += 4) {
                a0 += __shfl(h, srcbase | k, 64) * wh[k];
                a1 += __shfl(h, srcbase | (k + 1), 64) * wh[k + 1];
                a2 += __shfl(h, srcbase | (k + 2), 64) * wh[k + 2];
                a3 += __shfl(h, srcbase | (k + 3), 64) * wh[k + 3];
            }
            float x2 = (a0 + a1) + (a2 + a3);
            float e = __expf(2.f * x2);            // tanh = 1 - 2/(e^{2x}+1)
            h = 1.f - 2.f * __builtin_amdgcn_rcpf(e + 1.f);
        }
    }
}

// ---------------------------------------------------------------------------
// Kernel 2 (single GEMM pass): grid (125, 8). Each block: B-fragments loaded
// ONCE, then 4 row-tiles of {GEMM, exp-sum partials -> Asum, bf16 logits ->
// logit cache via LDS repack + coalesced stores}.
// ---------------------------------------------------------------------------
__global__ __launch_bounds__(256) void k_gemm_cache(
    const __bf16* __restrict__ hcat, const __bf16* __restrict__ h2oT,
    float* __restrict__ Asum, unsigned short* __restrict__ logit_u) {
    const int tid = threadIdx.x;
    const int wave = tid >> 6, lane = tid & 63;
    const int wm = wave >> 1, wn = wave & 1;
    const int lg = lane >> 4, lr = lane & 15;
    const int xcol = blockIdx.x;
    const int colbase = xcol * 256;

    bf16x8 bfr[8][2];
    load_bfrag(h2oT, xcol, wn, lg, lr, bfr);

    __shared__ float tsum[2][64];
    __shared__ float cbuf[32 * 260];   // 33.3 KB; pad 260 breaks conflicts

    for (int jt = 0; jt < 4; ++jt) {
        const int rowbase = (blockIdx.y * 4 + jt) * 64;
        f32x4 acc[2][8];
        tile_gemm(hcat, rowbase, wm, lg, lr, bfr, acc);

        // ---- sum-exp partials (max-free; |logit| bounded, f32 exp safe) ----
        float rs[2][4];
#pragma unroll
        for (int m = 0; m < 2; ++m)
#pragma unroll
            for (int r = 0; r < 4; ++r) {
                float s = 0.f;
#pragma unroll
                for (int n = 0; n < 8; ++n) s += __expf(acc[m][n][r]);
                rs[m][r] = s;
            }
#pragma unroll
        for (int mask = 1; mask < 16; mask <<= 1)
#pragma unroll
            for (int m = 0; m < 2; ++m)
#pragma unroll
                for (int r = 0; r < 4; ++r)
                    rs[m][r] += __shfl_xor(rs[m][r], mask, 64);
        if (lr == 0) {
#pragma unroll
            for (int m = 0; m < 2; ++m)
#pragma unroll
                for (int r = 0; r < 4; ++r)
                    tsum[wn][wm * 32 + m * 16 + lg * 4 + r] = rs[m][r];
        }
        __syncthreads();
        if (tid < 64)
            Asum[xcol * M_TOT + rowbase + tid] = tsum[0][tid] + tsum[1][tid];

        // ---- bf16 logit store via two-chunk LDS repack ----
#pragma unroll
        for (int c = 0; c < 2; ++c) {
            __syncthreads();           // WAR guard on cbuf/tsum reuse
#pragma unroll
            for (int n = 0; n < 8; ++n)
#pragma unroll
                for (int r = 0; r < 4; ++r)
                    cbuf[(wm * 16 + lg * 4 + r) * 260 + wn * 128 + n * 16 + lr] =
                        acc[c][n][r];
            __syncthreads();
#pragma unroll
            for (int it = 0; it < 8; ++it) {
                int idx4 = it * 256 + tid;     // f32x4 index in 32x256 chunk
                int lrow = idx4 >> 6;
                int col = (idx4 & 63) << 2;
                int grow = rowbase + (lrow >> 4) * 32 + c * 16 + (lrow & 15);
                f32x4 v = *(const f32x4*)&cbuf[lrow * 260 + col];
                u16x4 o;
                o.x = f2bf(v.x); o.y = f2bf(v.y);
                o.z = f2bf(v.z); o.w = f2bf(v.w);
                *(u16x4*)(logit_u + (size_t)grow * V_SZ + colbase + col) = o;
            }
        }
        __syncthreads();               // protect tsum before next jt
    }
}

// ---------------------------------------------------------------------------
// Kernel 3: reduce partials over 125 v-tiles -> lse[row] = log(sum)
// ---------------------------------------------------------------------------
__global__ __launch_bounds__(256) void k_lse(
    const float* __restrict__ Asum, float* __restrict__ lse) {
    const int row = blockIdx.x * 256 + threadIdx.x;
    float s = 0.f;
    for (int i = 0; i < NVT; ++i) s += Asum[i * M_TOT + row];
    lse[row] = logf(s);
}

// ---------------------------------------------------------------------------
// Kernel 4 (pure streaming): out[row][v] = bf16logit[row][v] - lse[row].
// Grid-stride, fully coalesced: 8B reads, 16B writes.
// ---------------------------------------------------------------------------
__global__ __launch_bounds__(256) void k_final(
    const unsigned short* __restrict__ logit_u, const float* __restrict__ lse,
    float* __restrict__ out) {
    const int gs = gridDim.x * 256;
    for (int i = blockIdx.x * 256 + threadIdx.x; i < NQ4; i += gs) {
        const int row = (unsigned)i / 8000u;          // V_SZ/4 per row
        u16x4 l4 = *(const u16x4*)(logit_u + (size_t)i * 4);
        const float ls = lse[row];
        f32x4 v;
        v.x = bf2f(l4.x) - ls;
        v.y = bf2f(l4.y) - ls;
        v.z = bf2f(l4.z) - ls;
        v.w = bf2f(l4.w) - ls;
        *(f32x4*)(out + (size_t)i * 4) = v;
    }
}

// ---------------------------------------------------------------------------
extern "C" void kernel_launch(void* const* d_in, const int* in_sizes, int n_in,
                              void* d_out, int out_size, void* d_ws, size_t ws_size,
                              hipStream_t stream) {
    (void)in_sizes; (void)n_in; (void)out_size; (void)ws_size;
    const int*   inp   = (const int*)d_in[0];
    const float* we    = (const float*)d_in[1];
    const float* i2h1  = (const float*)d_in[2];
    const float* i2h2  = (const float*)d_in[3];
    const float* h2o   = (const float*)d_in[4];
    const float* bias  = (const float*)d_in[5];
    const float* hinit = (const float*)d_in[6];
    float* out = (float*)d_out;
    char* ws = (char*)d_ws;
    unsigned short* hcat_u  = (unsigned short*)(ws);           //   262144 B
    unsigned short* h2oT_u  = (unsigned short*)(ws + 262144);  //  4096000 B
    float*          Asum    = (float*)(ws + 4358144);          //  1024000 B
    float*          lse     = (float*)(ws + 5382144);          //     8192 B
    unsigned short* logit_u = (unsigned short*)(ws + 5390336); // 131072000 B

    k_prep_rnn<<<157, 256, 0, stream>>>(inp, we, i2h1, i2h2, h2o, bias, hinit,
                                        hcat_u, h2oT_u);
    k_gemm_cache<<<dim3(NVT, 8), 256, 0, stream>>>(
        (const __bf16*)hcat_u, (const __bf16*)h2oT_u, Asum, logit_u);
    k_lse<<<8, 256, 0, stream>>>(Asum, lse);
    k_final<<<2048, 256, 0, stream>>>(logit_u, lse, out);
}